// Round 9
// baseline (163.602 us; speedup 1.0000x reference)
//
#include <hip/hip_runtime.h>
#include <stdint.h>

#define N_ANCH 4096
#define NCLS 8
#define CN (N_ANCH * NCLS)
#define SCORE_TH 0.5f
#define IOU_TH 0.5f
#define KSEL 11
#define MAX_DET 100
#define CAND_CAP 4096
#define TI 128                        // i-rows per block
#define TJ 64                         // j-cols per block (LDS-staged)
#define JOBS_PER_CLASS 1056           // sum_{ci=0}^{31} (2*ci+2) = 32*33

struct Params {
    const float* boxes; const float* cls; const float* poses; const float* conf;
    int* validList; int* mVal; int* minRank;
    int* surv; int* hist; int* blockCnt;
    int* rep;
    float* out;
};

__device__ __forceinline__ float area_f(float4 b) {
    return (b.z - b.x + 1.0f) * (b.w - b.y + 1.0f);
}

__device__ __forceinline__ float iou_f(float4 a, float areaA, float4 b, float areaB) {
    float x1 = fmaxf(a.x, b.x);
    float y1 = fmaxf(a.y, b.y);
    float x2 = fminf(a.z, b.z);
    float y2 = fminf(a.w, b.w);
    float wid = x2 - x1 + 1.0f;
    float hei = y2 - y1 + 1.0f;
    float inter = wid * hei;
    float den = areaA + areaB - inter;
    float ov = (den == 0.0f) ? 0.0f : (inter / den);
    if (wid <= 0.0f || hei <= 0.0f) ov = 0.0f;
    return ov;
}

// kS: 8 blocks (one per class). Single-pass ordered valid-list build
// (ballot all 16 chunks -> LDS, one-thread prefix, scatter) + all zero-init.
__global__ void __launch_bounds__(256) kS(Params p) {
    const int c = blockIdx.x;
    const int tid = threadIdx.x;
    const int lane = tid & 63, w = tid >> 6;
    const int cbase = c << 12;
    __shared__ unsigned long long smask[64];  // [16][4]
    __shared__ int sbase[16];

    for (int ch = 0; ch < 16; ch++) {
        int n = ch * 256 + tid;
        int flag = (p.cls[n * 8 + c] > SCORE_TH) ? 1 : 0;
        unsigned long long m = __ballot(flag);
        if (lane == 0) smask[ch * 4 + w] = m;
    }
    __syncthreads();
    if (tid == 0) {
        int run = 0;
        for (int ch = 0; ch < 16; ch++) {
            sbase[ch] = run;
            run += __popcll(smask[ch * 4]) + __popcll(smask[ch * 4 + 1]) +
                   __popcll(smask[ch * 4 + 2]) + __popcll(smask[ch * 4 + 3]);
        }
        p.mVal[c] = run;
    }
    __syncthreads();
    for (int ch = 0; ch < 16; ch++) {
        unsigned long long m = smask[ch * 4 + w];
        if ((m >> lane) & 1ull) {
            int rank = __popcll(m & ((1ull << lane) - 1ull));
            int wb = 0;
            for (int i = 0; i < w; i++) wb += __popcll(smask[ch * 4 + i]);
            p.validList[c * N_ANCH + sbase[ch] + wb + rank] = ch * 256 + tid;
        }
    }
    for (int i = tid; i < N_ANCH; i += 256) {
        p.surv[cbase + i] = 0;
        p.minRank[cbase + i] = 0x7FFFFFFF;
    }
    if (c == 0) {
        for (int i = tid; i < 1024; i += 256) p.hist[i] = 0;
        if (tid < 128) p.blockCnt[tid] = 0;
    }
}

// kM: rep-matrix min-rank scan. Block = (class, i-tile of 128 rows, j-tile of
// 64 cols, triangular: jb < ib+TI). 64-col LDS stage (boxes + areas), one
// thread per row, full-tile no-break scan, division-free IoU>0.5 predicate.
__global__ void __launch_bounds__(128) kM(Params p) {
    int bid = blockIdx.x;
    int c = bid / JOBS_PER_CLASS;
    int t = bid - c * JOBS_PER_CLASS;
    int ci = (int)((sqrtf(4.0f * (float)t + 1.0f) - 1.0f) * 0.5f);
    while ((ci + 1) * (ci + 2) <= t) ci++;   // block start for ci: ci*(ci+1)
    while (ci * (ci + 1) > t) ci--;
    int jt = t - ci * (ci + 1);              // jt in [0, 2*ci+1]
    int mc = p.mVal[c];
    int ib = ci * TI, jb = jt * TJ;
    if (ib >= mc || jb >= mc) return;
    int tid = threadIdx.x;
    int cbase = c << 12;
    const int* vl = p.validList + cbase;
    const float4* boxes4 = (const float4*)p.boxes;
    __shared__ float4 sB[TJ];
    __shared__ float sA[TJ];
    if (tid < TJ && jb + tid < mc) {
        int vj = vl[jb + tid];
        float4 b = boxes4[vj * 8 + c];
        sB[tid] = b;
        sA[tid] = area_f(b);
    }
    __syncthreads();
    int i = ib + tid;
    if (i >= mc) return;
    int limit = min(TJ, i - jb);        // strictly j-rank < i-rank (diag partial)
    limit = min(limit, mc - jb);
    if (limit <= 0) return;
    int k = vl[i];
    float4 bk = boxes4[k * 8 + c];
    float ak = area_f(bk);
    int lmin = 0x7FFFFFFF;
    #pragma unroll 4
    for (int r = 0; r < limit; r++) {
        float4 bj = sB[r];
        float x1 = fmaxf(bk.x, bj.x);
        float y1 = fmaxf(bk.y, bj.y);
        float x2 = fminf(bk.z, bj.z);
        float y2 = fminf(bk.w, bj.w);
        float wid = x2 - x1 + 1.0f;
        float hei = y2 - y1 + 1.0f;
        float inter = wid * hei;
        float den = ak + sA[r] - inter;
        bool m = (wid > 0.0f) && (hei > 0.0f) && (inter > 0.5f * den);
        if (m && r < lmin) lmin = r;
    }
    if (lmin != 0x7FFFFFFF) atomicMin(&p.minRank[cbase + i], jb + lmin);
}

// kF: finalize rep + surv (first-setter also bumps blockCnt + score hist).
__global__ void __launch_bounds__(256) kF(Params p) {
    int t = blockIdx.x * 256 + threadIdx.x;
    int c = t >> 12;
    int i = t & (N_ANCH - 1);   // rank
    if (i >= p.mVal[c]) return;
    int cbase = c << 12;
    const int* vl = p.validList + cbase;
    const float4* boxes4 = (const float4*)p.boxes;
    int k = vl[i];
    int mr = p.minRank[t];
    if (mr > i) mr = i;         // self
    int ja = vl[mr];
    p.rep[cbase + k] = ja;
    if (mr < i) {
        float4 bk = boxes4[k * 8 + c];
        float4 bj = boxes4[ja * 8 + c];
        float ov = iou_f(bk, area_f(bk), bj, area_f(bj));
        float bcv = (1.0f - ov) * p.conf[k * 8 + c];
        if (bcv != 0.0f) {
            int old = atomicExch(&p.surv[cbase + ja], 1);
            if (old == 0) {
                atomicAdd(&p.blockCnt[(cbase + ja) >> 8], 1);
                unsigned bits = __float_as_uint(p.cls[ja * 8 + c]);
                int bb = (int)((bits - 0x3F000000u) >> 13);
                int bkt = bb < 0 ? 0 : (bb > 1023 ? 1023 : bb);
                atomicAdd(&p.hist[bkt], 1);
            }
        }
    }
}

// kO: block 0 = histogram threshold + survivor-score gather + bitonic sort
// -> top-100 scores; blocks 1..100 = locate flat-order survivor #s via
// blockCnt prefix + chunk ballot-rank, then cluster gather + KSEL + averages.
__global__ void __launch_bounds__(256) kO(Params p) {
    const int bid = blockIdx.x;
    const int tid = threadIdx.x;
    const int lane = tid & 63, w = tid >> 6;
    __shared__ __align__(16) unsigned char SMEM[32768];
    __shared__ int sCnt[128];
    __shared__ int sSfx[256];
    __shared__ int s_misc[8];
    __shared__ int s_sp;
    __shared__ int s_ksel[KSEL];
    __shared__ unsigned long long s_red[5];
    const float4* boxes4 = (const float4*)p.boxes;

    // common: exclusive prefix of blockCnt + total survivor count
    if (tid < 128) sCnt[tid] = p.blockCnt[tid];
    __syncthreads();
    if (tid == 0) {
        int run = 0;
        for (int i = 0; i < 128; i++) { int v = sCnt[i]; sCnt[i] = run; run += v; }
        s_misc[1] = run;   // count
    }
    __syncthreads();
    int count = s_misc[1];

    if (bid == 0) {
        // threshold bucket t0 (suffix sums of hist)
        if (tid == 0) s_misc[0] = 0;
        int part = p.hist[4 * tid] + p.hist[4 * tid + 1] +
                   p.hist[4 * tid + 2] + p.hist[4 * tid + 3];
        sSfx[tid] = part;
        __syncthreads();
        if (tid == 0) {
            int run2 = 0;
            for (int i = 255; i >= 0; i--) { int v = sSfx[i]; sSfx[i] = run2; run2 += v; }
        }
        __syncthreads();
        int target = count < MAX_DET ? count : MAX_DET;
        int S = sSfx[tid];
        int found = -1;
        for (int b = 4 * tid + 3; b >= 4 * tid; b--) {
            S += p.hist[b];
            if (found < 0 && S >= target) found = b;
        }
        if (found >= 0) atomicMax(&s_misc[0], found);
        __syncthreads();
        int t0 = s_misc[0];
        // gather qualifying survivor scores straight into LDS
        float* s = (float*)SMEM;
        if (tid == 0) s_misc[2] = 0;
        __syncthreads();
        for (int base = 0; base < CN; base += 256) {
            int q = base + tid;
            if (p.surv[q] != 0) {
                int c = q >> 12, n = q & (N_ANCH - 1);
                float sc = p.cls[n * 8 + c];
                unsigned bits = __float_as_uint(sc);
                int bb = (int)((bits - 0x3F000000u) >> 13);
                int bkt = bb < 0 ? 0 : (bb > 1023 ? 1023 : bb);
                if (bkt >= t0) {
                    int id = atomicAdd(&s_misc[2], 1);
                    if (id < CAND_CAP) s[id] = sc;
                }
            }
        }
        __syncthreads();
        int cc = s_misc[2]; if (cc > CAND_CAP) cc = CAND_CAP;
        int n = 128; while (n < cc) n <<= 1;
        for (int i = tid; i < n; i += 256) s[i] = (i < cc) ? -s[i] : 1e38f;
        __syncthreads();
        for (int kk = 2; kk <= n; kk <<= 1) {
            for (int jj = kk >> 1; jj > 0; jj >>= 1) {
                for (int i = tid; i < n; i += 256) {
                    int ixj = i ^ jj;
                    if (ixj > i) {
                        float a = s[i], b2 = s[ixj];
                        bool up = ((i & kk) == 0);
                        if (up ? (a > b2) : (a < b2)) { s[i] = b2; s[ixj] = a; }
                    }
                }
                __syncthreads();
            }
        }
        if (tid < MAX_DET) p.out[tid] = (tid < count) ? -s[tid] : -1.0f;
    } else {
        int sIdx = bid - 1;
        if (sIdx >= count) {
            if (tid == 0) { p.out[100 + sIdx] = -1.0f; p.out[1400 + sIdx] = -1.0f; }
            if (tid < 12) p.out[200 + sIdx * 12 + tid] = -1.0f;
            if (tid >= 16 && tid < 20) p.out[1500 + sIdx * 4 + (tid - 16)] = -1.0f;
        } else {
            // locate chunk holding flat-order survivor #sIdx
            if (tid == 0) {
                int ch = 0;
                for (int i = 0; i < 128; i++) { if (sCnt[i] <= sIdx) ch = i; else break; }
                s_misc[3] = ch;
            }
            __syncthreads();
            int ch = s_misc[3];
            int ls = sIdx - sCnt[ch];
            int qq = ch * 256 + tid;
            int flag = p.surv[qq] != 0;
            unsigned long long m = __ballot(flag);
            if (lane == 0) s_misc[4 + w] = __popcll(m);
            __syncthreads();
            int wbase = 0;
            for (int i = 0; i < w; i++) wbase += s_misc[4 + i];
            int rank = wbase + __popcll(m & ((1ull << lane) - 1ull));
            if (flag && rank == ls) s_sp = qq;
            __syncthreads();
            int sp = s_sp;
            int c = sp >> 12;
            int r = sp & (N_ANCH - 1);
            int cbase = c << 12;
            unsigned long long* keyArr = (unsigned long long*)SMEM;  // 4096 x 8 B
            if (tid == 0) s_misc[0] = 0;  // nm
            __syncthreads();
            float4 br = boxes4[r * 8 + c];
            float ar = area_f(br);
            for (int k = tid; k < N_ANCH; k += 256) {
                if (k != r && p.cls[k * 8 + c] > SCORE_TH && p.rep[cbase + k] == r) {
                    float4 bkk = boxes4[k * 8 + c];
                    float ov = iou_f(br, ar, bkk, area_f(bkk));
                    float bcv = (1.0f - ov) * p.conf[k * 8 + c];
                    if (bcv != 0.0f) {
                        int id = atomicAdd(&s_misc[0], 1);
                        keyArr[id] = ((unsigned long long)__float_as_uint(bcv) << 32) | (unsigned)k;
                    }
                }
            }
            __syncthreads();
            int nm = s_misc[0];
            int dn = nm < KSEL ? nm : KSEL;
            unsigned long long lastBest = ~0ull;
            for (int j = 0; j < dn; j++) {
                unsigned long long bk = ~0ull;
                for (int i = tid; i < nm; i += 256) {
                    unsigned long long v = keyArr[i];
                    if (v == lastBest) { keyArr[i] = ~0ull; v = ~0ull; }
                    if (v < bk) bk = v;
                }
                for (int off = 32; off > 0; off >>= 1) {
                    unsigned long long o = __shfl_down(bk, off);
                    if (o < bk) bk = o;
                }
                if (lane == 0) s_red[w] = bk;
                __syncthreads();
                if (tid == 0) {
                    unsigned long long B = s_red[0];
                    for (int q2 = 1; q2 < 4; q2++) if (s_red[q2] < B) B = s_red[q2];
                    s_red[4] = B;
                    s_ksel[j] = (int)(B & 0xFFFFFFFFull);
                }
                __syncthreads();
                lastBest = s_red[4];
            }
            float fdn = (float)(dn > 0 ? dn : 1);
            if (tid < 12) {
                float ssum = 0.0f;
                for (int j = 0; j < dn; j++) {
                    int k = s_ksel[j];
                    ssum += p.poses[(k * 8 + c) * 12 + tid];
                }
                p.out[200 + sIdx * 12 + tid] = ssum / fdn;
            } else if (tid < 16) {
                int d = tid - 12;
                float ssum = 0.0f;
                for (int j = 0; j < dn; j++) {
                    int k = s_ksel[j];
                    const float* bb2 = (const float*)&boxes4[k * 8 + c];
                    ssum += bb2[d];
                }
                p.out[1500 + sIdx * 4 + d] = ssum / fdn;
            } else if (tid == 16) {
                p.out[100 + sIdx] = (float)c;
            } else if (tid == 17) {
                p.out[1400 + sIdx] = (float)r;
            }
        }
    }
}

extern "C" void kernel_launch(void* const* d_in, const int* in_sizes, int n_in,
                              void* d_out, int out_size, void* d_ws, size_t ws_size,
                              hipStream_t stream) {
    Params hp;
    hp.boxes = (const float*)d_in[1];
    hp.cls   = (const float*)d_in[2];
    hp.poses = (const float*)d_in[3];
    hp.conf  = (const float*)d_in[4];
    hp.out   = (float*)d_out;

    char* ws = (char*)d_ws;
    size_t off = 0;
    auto alloc = [&](size_t bytes) {
        void* pp = ws + off;
        off += (bytes + 255) & ~(size_t)255;
        return pp;
    };
    hp.validList = (int*)alloc(CN * sizeof(int));
    hp.mVal      = (int*)alloc(64);
    hp.minRank   = (int*)alloc(CN * sizeof(int));
    hp.surv      = (int*)alloc(CN * sizeof(int));
    hp.hist      = (int*)alloc(1024 * sizeof(int));
    hp.blockCnt  = (int*)alloc(128 * sizeof(int));
    hp.rep       = (int*)alloc(CN * sizeof(int));

    kS<<<NCLS, 256, 0, stream>>>(hp);                    // 8 blocks
    kM<<<NCLS * JOBS_PER_CLASS, TI, 0, stream>>>(hp);    // 8448 blocks
    kF<<<CN / 256, 256, 0, stream>>>(hp);                // 128 blocks
    kO<<<MAX_DET + 1, 256, 0, stream>>>(hp);             // 101 blocks
}

// Round 11
// 118.346 us; speedup vs baseline: 1.3824x; 1.3824x over previous
//
#include <hip/hip_runtime.h>
#include <stdint.h>

#define N_ANCH 4096
#define NCLS 8
#define CN (N_ANCH * NCLS)
#define SCORE_TH 0.5f
#define IOU_TH 0.5f
#define KSEL 11
#define MAX_DET 100
#define CAND_CAP 4096
#define TI 128                        // i-rows per block
#define TJ 64                         // j-cols per block (LDS-staged)
#define JOBS_PER_CLASS 1056           // sum_{ci=0}^{31} (2*ci+2) = 32*33

struct Params {
    const float* boxes; const float* cls; const float* poses; const float* conf;
    int* validList; int* mVal; int* minRank;
    int* surv; int* hist; int* blockCnt; int* gcnt;
    int* rep; int* sel; int* count_g; float* cand;
    float* out;
};

__device__ __forceinline__ float area_f(float4 b) {
    return (b.z - b.x + 1.0f) * (b.w - b.y + 1.0f);
}

__device__ __forceinline__ float iou_f(float4 a, float areaA, float4 b, float areaB) {
    float x1 = fmaxf(a.x, b.x);
    float y1 = fmaxf(a.y, b.y);
    float x2 = fminf(a.z, b.z);
    float y2 = fminf(a.w, b.w);
    float wid = x2 - x1 + 1.0f;
    float hei = y2 - y1 + 1.0f;
    float inter = wid * hei;
    float den = areaA + areaB - inter;
    float ov = (den == 0.0f) ? 0.0f : (inter / den);
    if (wid <= 0.0f || hei <= 0.0f) ov = 0.0f;
    return ov;
}

// kS: 8 blocks (one per class). Single-pass ordered valid-list build
// (ballot all 16 chunks -> LDS, one-thread prefix, scatter) + all zero-init
// (surv, minRank=INF, rep=-1, hist, blockCnt, gcnt).
__global__ void __launch_bounds__(256) kS(Params p) {
    const int c = blockIdx.x;
    const int tid = threadIdx.x;
    const int lane = tid & 63, w = tid >> 6;
    const int cbase = c << 12;
    __shared__ unsigned long long smask[64];  // [16][4]
    __shared__ int sbase[16];

    for (int ch = 0; ch < 16; ch++) {
        int n = ch * 256 + tid;
        int flag = (p.cls[n * 8 + c] > SCORE_TH) ? 1 : 0;
        unsigned long long m = __ballot(flag);
        if (lane == 0) smask[ch * 4 + w] = m;
    }
    __syncthreads();
    if (tid == 0) {
        int run = 0;
        for (int ch = 0; ch < 16; ch++) {
            sbase[ch] = run;
            run += __popcll(smask[ch * 4]) + __popcll(smask[ch * 4 + 1]) +
                   __popcll(smask[ch * 4 + 2]) + __popcll(smask[ch * 4 + 3]);
        }
        p.mVal[c] = run;
    }
    __syncthreads();
    for (int ch = 0; ch < 16; ch++) {
        unsigned long long m = smask[ch * 4 + w];
        if ((m >> lane) & 1ull) {
            int rank = __popcll(m & ((1ull << lane) - 1ull));
            int wb = 0;
            for (int i = 0; i < w; i++) wb += __popcll(smask[ch * 4 + i]);
            p.validList[c * N_ANCH + sbase[ch] + wb + rank] = ch * 256 + tid;
        }
    }
    for (int i = tid; i < N_ANCH; i += 256) {
        p.surv[cbase + i] = 0;
        p.minRank[cbase + i] = 0x7FFFFFFF;
        p.rep[cbase + i] = -1;   // invalid anchors never match rep==r tests
    }
    if (c == 0) {
        for (int i = tid; i < 1024; i += 256) p.hist[i] = 0;
        if (tid < 128) p.blockCnt[tid] = 0;
        if (tid == 0) *p.gcnt = 0;
    }
}

// kM: rep-matrix min-rank scan. Block = (class, i-tile of 128 rows, j-tile of
// 64 cols, triangular: jb < ib+TI). 64-col LDS stage (boxes + areas), one
// thread per row, full-tile no-break scan (unroll 8 -> deep ILP), division-
// free IoU>0.5 predicate (inter > 0.5*den).
__global__ void __launch_bounds__(128) kM(Params p) {
    int bid = blockIdx.x;
    int c = bid / JOBS_PER_CLASS;
    int t = bid - c * JOBS_PER_CLASS;
    int ci = (int)((sqrtf(4.0f * (float)t + 1.0f) - 1.0f) * 0.5f);
    while ((ci + 1) * (ci + 2) <= t) ci++;   // block start for ci: ci*(ci+1)
    while (ci * (ci + 1) > t) ci--;
    int jt = t - ci * (ci + 1);              // jt in [0, 2*ci+1]
    int mc = p.mVal[c];
    int ib = ci * TI, jb = jt * TJ;
    if (ib >= mc || jb >= mc) return;
    int tid = threadIdx.x;
    int cbase = c << 12;
    const int* vl = p.validList + cbase;
    const float4* boxes4 = (const float4*)p.boxes;
    __shared__ float4 sB[TJ];
    __shared__ float sA[TJ];
    if (tid < TJ && jb + tid < mc) {
        int vj = vl[jb + tid];
        float4 b = boxes4[vj * 8 + c];
        sB[tid] = b;
        sA[tid] = area_f(b);
    }
    __syncthreads();
    int i = ib + tid;
    if (i >= mc) return;
    int limit = min(TJ, i - jb);        // strictly j-rank < i-rank (diag partial)
    limit = min(limit, mc - jb);
    if (limit <= 0) return;
    int k = vl[i];
    float4 bk = boxes4[k * 8 + c];
    float ak = area_f(bk);
    int lmin = 0x7FFFFFFF;
    #pragma unroll 8
    for (int r = 0; r < limit; r++) {
        float4 bj = sB[r];
        float x1 = fmaxf(bk.x, bj.x);
        float y1 = fmaxf(bk.y, bj.y);
        float x2 = fminf(bk.z, bj.z);
        float y2 = fminf(bk.w, bj.w);
        float wid = x2 - x1 + 1.0f;
        float hei = y2 - y1 + 1.0f;
        float inter = wid * hei;
        float den = ak + sA[r] - inter;
        bool m = (wid > 0.0f) && (hei > 0.0f) && (inter > 0.5f * den);
        if (m && r < lmin) lmin = r;
    }
    if (lmin != 0x7FFFFFFF) atomicMin(&p.minRank[cbase + i], jb + lmin);
}

// kF: finalize rep + surv (first-setter also bumps blockCnt + score hist).
__global__ void __launch_bounds__(256) kF(Params p) {
    int t = blockIdx.x * 256 + threadIdx.x;
    int c = t >> 12;
    int i = t & (N_ANCH - 1);   // rank
    if (i >= p.mVal[c]) return;
    int cbase = c << 12;
    const int* vl = p.validList + cbase;
    const float4* boxes4 = (const float4*)p.boxes;
    int k = vl[i];
    int mr = p.minRank[t];
    if (mr > i) mr = i;         // self
    int ja = vl[mr];
    p.rep[cbase + k] = ja;
    if (mr < i) {
        float4 bk = boxes4[k * 8 + c];
        float4 bj = boxes4[ja * 8 + c];
        float ov = iou_f(bk, area_f(bk), bj, area_f(bj));
        float bcv = (1.0f - ov) * p.conf[k * 8 + c];
        if (bcv != 0.0f) {
            int old = atomicExch(&p.surv[cbase + ja], 1);
            if (old == 0) {
                atomicAdd(&p.blockCnt[(cbase + ja) >> 8], 1);
                unsigned bits = __float_as_uint(p.cls[ja * 8 + c]);
                int bb = (int)((bits - 0x3F000000u) >> 13);
                int bkt = bb < 0 ? 0 : (bb > 1023 ? 1023 : bb);
                atomicAdd(&p.hist[bkt], 1);
            }
        }
    }
}

// kG: 128 blocks. Redundant chunk-prefix + histogram threshold, ordered
// sel-write of first 100 survivors (flat order), candidate score gather.
__global__ void __launch_bounds__(256) kG(Params p) {
    const int bid = blockIdx.x;
    const int tid = threadIdx.x;
    const int lane = tid & 63, w = tid >> 6;
    __shared__ int sCnt[128];
    __shared__ int sSfx[256];
    __shared__ int s_misc[8];

    if (tid == 0) s_misc[0] = 0;  // thrB
    if (tid < 128) sCnt[tid] = p.blockCnt[tid];
    int part = p.hist[4 * tid] + p.hist[4 * tid + 1] +
               p.hist[4 * tid + 2] + p.hist[4 * tid + 3];
    sSfx[tid] = part;
    __syncthreads();
    if (tid == 0) {
        int run = 0, myoff = 0;
        for (int i = 0; i < 128; i++) {
            if (i == bid) myoff = run;
            run += sCnt[i];
        }
        s_misc[1] = run;    // total survivor count
        s_misc[2] = myoff;  // this chunk's base offset
        if (bid == 0) *p.count_g = run;
        int run2 = 0;
        for (int i = 255; i >= 0; i--) { int v = sSfx[i]; sSfx[i] = run2; run2 += v; }
    }
    __syncthreads();
    int count = s_misc[1];
    int target = count < MAX_DET ? count : MAX_DET;
    int S = sSfx[tid];
    int found = -1;
    for (int b = 4 * tid + 3; b >= 4 * tid; b--) {
        S += p.hist[b];
        if (found < 0 && S >= target) found = b;
    }
    if (found >= 0) atomicMax(&s_misc[0], found);
    __syncthreads();
    int t0 = s_misc[0];

    // ordered gather
    int q = bid * 256 + tid;
    int c = q >> 12, n = q & (N_ANCH - 1);
    int flag = p.surv[q] != 0;
    unsigned long long mask = __ballot(flag);
    if (lane == 0) s_misc[4 + w] = __popcll(mask);
    __syncthreads();
    int rank = __popcll(mask & ((1ull << lane) - 1ull));
    int wbase = 0;
    for (int i = 0; i < w; i++) wbase += s_misc[4 + i];
    int idx = s_misc[2] + wbase + rank;
    if (flag && idx < MAX_DET) p.sel[idx] = q;
    if (flag) {
        float sc = p.cls[n * 8 + c];
        unsigned bits = __float_as_uint(sc);
        int bb = (int)((bits - 0x3F000000u) >> 13);
        int bkt = bb < 0 ? 0 : (bb > 1023 ? 1023 : bb);
        if (bkt >= t0) {
            int id = atomicAdd(p.gcnt, 1);
            if (id < CAND_CAP) p.cand[id] = sc;
        }
    }
}

// kO: block 0 = bitonic sort of candidate scores -> top-100 scores;
// blocks 1..100 = per-slot cluster gather (rep==r only; rep=-1 for invalid)
// + KSEL selection + averages.
__global__ void __launch_bounds__(256) kO(Params p) {
    const int bid = blockIdx.x;
    const int tid = threadIdx.x;
    const int lane = tid & 63, w = tid >> 6;
    __shared__ __align__(16) unsigned char SMEM[32768];
    __shared__ int s_misc[8];
    __shared__ int s_ksel[KSEL];
    __shared__ unsigned long long s_red[5];
    const float4* boxes4 = (const float4*)p.boxes;

    if (bid == 0) {
        float* s = (float*)SMEM;
        int cc = *p.gcnt; if (cc > CAND_CAP) cc = CAND_CAP;
        int count = *p.count_g;
        int n = 128; while (n < cc) n <<= 1;
        for (int i = tid; i < n; i += 256) s[i] = (i < cc) ? -p.cand[i] : 1e38f;
        __syncthreads();
        for (int kk = 2; kk <= n; kk <<= 1) {
            for (int jj = kk >> 1; jj > 0; jj >>= 1) {
                for (int i = tid; i < n; i += 256) {
                    int ixj = i ^ jj;
                    if (ixj > i) {
                        float a = s[i], b2 = s[ixj];
                        bool up = ((i & kk) == 0);
                        if (up ? (a > b2) : (a < b2)) { s[i] = b2; s[ixj] = a; }
                    }
                }
                __syncthreads();
            }
        }
        if (tid < MAX_DET) p.out[tid] = (tid < count) ? -s[tid] : -1.0f;
    } else {
        int s = bid - 1;
        int count = *p.count_g;
        if (s >= count) {
            if (tid == 0) { p.out[100 + s] = -1.0f; p.out[1400 + s] = -1.0f; }
            if (tid < 12) p.out[200 + s * 12 + tid] = -1.0f;
            if (tid >= 16 && tid < 20) p.out[1500 + s * 4 + (tid - 16)] = -1.0f;
        } else {
            int sp = p.sel[s];
            int c = sp >> 12;
            int r = sp & (N_ANCH - 1);
            int cbase = c << 12;
            unsigned long long* keyArr = (unsigned long long*)SMEM;  // 4096 x 8 B
            if (tid == 0) s_misc[0] = 0;  // nm
            __syncthreads();
            float4 br = boxes4[r * 8 + c];
            float ar = area_f(br);
            for (int k = tid; k < N_ANCH; k += 256) {
                if (k != r && p.rep[cbase + k] == r) {     // rep=-1 for invalid
                    float4 bkk = boxes4[k * 8 + c];
                    float ov = iou_f(br, ar, bkk, area_f(bkk));
                    float bcv = (1.0f - ov) * p.conf[k * 8 + c];
                    if (bcv != 0.0f) {
                        int id = atomicAdd(&s_misc[0], 1);
                        keyArr[id] = ((unsigned long long)__float_as_uint(bcv) << 32) | (unsigned)k;
                    }
                }
            }
            __syncthreads();
            int nm = s_misc[0];
            int dn = nm < KSEL ? nm : KSEL;
            unsigned long long lastBest = ~0ull;
            for (int j = 0; j < dn; j++) {
                unsigned long long bk = ~0ull;
                for (int i = tid; i < nm; i += 256) {
                    unsigned long long v = keyArr[i];
                    if (v == lastBest) { keyArr[i] = ~0ull; v = ~0ull; }
                    if (v < bk) bk = v;
                }
                for (int off = 32; off > 0; off >>= 1) {
                    unsigned long long o = __shfl_down(bk, off);
                    if (o < bk) bk = o;
                }
                if (lane == 0) s_red[w] = bk;
                __syncthreads();
                if (tid == 0) {
                    unsigned long long B = s_red[0];
                    for (int q2 = 1; q2 < 4; q2++) if (s_red[q2] < B) B = s_red[q2];
                    s_red[4] = B;
                    s_ksel[j] = (int)(B & 0xFFFFFFFFull);
                }
                __syncthreads();
                lastBest = s_red[4];
            }
            float fdn = (float)(dn > 0 ? dn : 1);
            if (tid < 12) {
                float ssum = 0.0f;
                for (int j = 0; j < dn; j++) {
                    int k = s_ksel[j];
                    ssum += p.poses[(k * 8 + c) * 12 + tid];
                }
                p.out[200 + s * 12 + tid] = ssum / fdn;
            } else if (tid < 16) {
                int d = tid - 12;
                float ssum = 0.0f;
                for (int j = 0; j < dn; j++) {
                    int k = s_ksel[j];
                    const float* bb2 = (const float*)&boxes4[k * 8 + c];
                    ssum += bb2[d];
                }
                p.out[1500 + s * 4 + d] = ssum / fdn;
            } else if (tid == 16) {
                p.out[100 + s] = (float)c;
            } else if (tid == 17) {
                p.out[1400 + s] = (float)r;
            }
        }
    }
}

extern "C" void kernel_launch(void* const* d_in, const int* in_sizes, int n_in,
                              void* d_out, int out_size, void* d_ws, size_t ws_size,
                              hipStream_t stream) {
    Params hp;
    hp.boxes = (const float*)d_in[1];
    hp.cls   = (const float*)d_in[2];
    hp.poses = (const float*)d_in[3];
    hp.conf  = (const float*)d_in[4];
    hp.out   = (float*)d_out;

    char* ws = (char*)d_ws;
    size_t off = 0;
    auto alloc = [&](size_t bytes) {
        void* pp = ws + off;
        off += (bytes + 255) & ~(size_t)255;
        return pp;
    };
    hp.validList = (int*)alloc(CN * sizeof(int));
    hp.mVal      = (int*)alloc(64);
    hp.minRank   = (int*)alloc(CN * sizeof(int));
    hp.surv      = (int*)alloc(CN * sizeof(int));
    hp.hist      = (int*)alloc(1024 * sizeof(int));
    hp.blockCnt  = (int*)alloc(128 * sizeof(int));
    hp.gcnt      = (int*)alloc(64);
    hp.rep       = (int*)alloc(CN * sizeof(int));
    hp.sel       = (int*)alloc(MAX_DET * sizeof(int));
    hp.count_g   = (int*)alloc(64);
    hp.cand      = (float*)alloc(CAND_CAP * sizeof(float));

    kS<<<NCLS, 256, 0, stream>>>(hp);                    // 8 blocks
    kM<<<NCLS * JOBS_PER_CLASS, TI, 0, stream>>>(hp);    // 8448 blocks
    kF<<<CN / 256, 256, 0, stream>>>(hp);                // 128 blocks
    kG<<<CN / 256, 256, 0, stream>>>(hp);                // 128 blocks
    kO<<<MAX_DET + 1, 256, 0, stream>>>(hp);             // 101 blocks
}